// Round 1
// baseline (123.504 us; speedup 1.0000x reference)
//
#include <hip/hip_runtime.h>

// logits = relu(T1[q] + sum_s T2[t_s]) @ W2^T + b2, vocab=64 so layer-1 is
// 9 table-row gathers. Tables stored as bf16 in LDS (row stride 144 B =
// 36 dwords) -> half the LDS traffic of fp32 and packed dwords are already
// in MFMA A-fragment byte order.
//
// R0 changes vs previous best (117 us):
//  - B-fragment remap: lane l15 holds W2 rows l15*4+nt (was nt*16+l15), so
//    each lane's 4 nt-tile outputs are 4 contiguous logits -> epilogue is
//    4 coalesced nontemporal global_store_dwordx4 instead of 16 scalar
//    stores scattered stride-64.
//  - Both iterations' seqs/qtok loads hoisted above iter-0 compute so the
//    second HBM round-trip hides under the first iteration's work.
//  - prep_kernel dot product vectorized (f32x4).

#define RSTRIDE_W 36                    // dwords per row (32 data + 4 pad)
#define T2_OFF_W  (64 * RSTRIDE_W)      // 2304
#define LDS_DW    (2 * 64 * RSTRIDE_W)  // 4608 dwords = 18432 B

typedef __attribute__((ext_vector_type(4))) float f32x4;
typedef __attribute__((ext_vector_type(4))) int   i32x4;
typedef __attribute__((ext_vector_type(8))) short bf16x8;

// round-to-nearest-even fp32 -> bf16 (avoids ROCm 7.2 bf16-header overload
// ambiguity with __float2bfloat16_rn)
__device__ __forceinline__ unsigned short f2bf(float x) {
  union { float f; unsigned u; } c; c.f = x;
  unsigned u = c.u + 0x7fffu + ((c.u >> 16) & 1u);
  return (unsigned short)(u >> 16);
}
__device__ __forceinline__ unsigned pkbf2(float a, float b) {
  return (unsigned)f2bf(a) | ((unsigned)f2bf(b) << 16);
}

// T1 (query half, b1 folded) and T2 (memory half, 1/8 folded), bf16.
// grid 128: block = (half, token). thread j = output feature.
__global__ void prep_kernel(const float* __restrict__ embed,
                            const float* __restrict__ W1,
                            const float* __restrict__ b1,
                            unsigned short* __restrict__ T) {
  const int t    = blockIdx.x & 63;
  const int half = blockIdx.x >> 6;
  const int j    = threadIdx.x;
  const f32x4* w4 = (const f32x4*)(W1 + j * 128 + half * 64);
  const f32x4* e4 = (const f32x4*)(embed + t * 64);
  float acc = 0.f;
#pragma unroll
  for (int k = 0; k < 16; ++k) {
    f32x4 a = w4[k], b = e4[k];
    acc += a[0] * b[0] + a[1] * b[1] + a[2] * b[2] + a[3] * b[3];
  }
  const float outv = half ? acc * 0.125f : acc + b1[j];
  T[half * (64 * 2 * RSTRIDE_W) + t * (2 * RSTRIDE_W) + j] = f2bf(outv);
}

// 2048 blocks x 256 threads; each wave: 2 iters x 16 elements (one MFMA
// tile row). Lane (qd=lane>>4, m=lane&15) gathers features qd*8..+7 (ks0)
// and 32+qd*8..+7 (ks1) of its element's 9 table rows as packed bf16,
// accumulates in fp32 via shift/mask unpack, ReLUs, repacks to the MFMA
// A-fragment, then 2 MFMAs per 16-col output tile.
__global__ __launch_bounds__(256, 4) void lru_kernel(
    const int*      __restrict__ seqs,
    const int*      __restrict__ qtok,
    const float*    __restrict__ W2,
    const float*    __restrict__ b2,
    const unsigned* __restrict__ T,
    float*          __restrict__ out) {
  __shared__ __align__(16) unsigned lds[LDS_DW];
  const int tid = threadIdx.x;

  {  // stage tables (1152 uint4 = 4*256 + 128)
    const uint4* src = (const uint4*)T;
    uint4*       dst = (uint4*)lds;
#pragma unroll
    for (int r = 0; r < 4; ++r) dst[tid + r * 256] = src[tid + r * 256];
    if (tid < 128) dst[tid + 1024] = src[tid + 1024];
  }

  const int lane = tid & 63;
  const int wv   = tid >> 6;
  const int qd   = lane >> 4;
  const int l15  = lane & 15;

  // B-fragments from W2 (fp32 global): lane holds n-col l15 of MFMA tile nt,
  // mapped to W2 row (l15*4 + nt) so nt-outputs are contiguous logits.
  bf16x8 bfr[4][2];
  float  bb[4];
#pragma unroll
  for (int nt = 0; nt < 4; ++nt) {
    const int    row = l15 * 4 + nt;
    const float* wr  = W2 + row * 64 + qd * 8;
#pragma unroll
    for (int ks = 0; ks < 2; ++ks) {
      f32x4 w0 = *(const f32x4*)(wr + ks * 32);
      f32x4 w1 = *(const f32x4*)(wr + ks * 32 + 4);
      union { bf16x8 s; unsigned u[4]; } ub;
      ub.u[0] = pkbf2(w0[0], w0[1]);
      ub.u[1] = pkbf2(w0[2], w0[3]);
      ub.u[2] = pkbf2(w1[0], w1[1]);
      ub.u[3] = pkbf2(w1[2], w1[3]);
      bfr[nt][ks] = ub.s;
    }
    bb[nt] = b2[row];
  }

  const int base = blockIdx.x * 128 + wv * 32;

  // prefetch tokens for BOTH iterations before any compute
  i32x4 tc[2][3];
  int   tq[2];
#pragma unroll
  for (int it = 0; it < 2; ++it) {
    const int  elem = base + it * 16 + l15;
    const int* srow = seqs + elem * 24;
    tc[it][0] = __builtin_nontemporal_load((const i32x4*)(srow + 12));
    tc[it][1] = __builtin_nontemporal_load((const i32x4*)(srow + 16));
    tc[it][2] = __builtin_nontemporal_load((const i32x4*)(srow + 20));
    tq[it]    = __builtin_nontemporal_load(qtok + elem);
  }
  __syncthreads();

#pragma unroll
  for (int it = 0; it < 2; ++it) {
    const int b0 = base + it * 16;
    const int tk[8] = {tc[it][0][3], tc[it][1][0], tc[it][1][1], tc[it][1][2],
                       tc[it][1][3], tc[it][2][0], tc[it][2][1], tc[it][2][2]};
    const int qt = tq[it];

    // fp32 accumulators: [0..3]=ks0 dwords, [4..7]=ks1 dwords (lo/hi pair)
    float alo[8], ahi[8];
    {
      const unsigned* r1 = lds + qt * RSTRIDE_W + qd * 4;
      uint4 d0 = *(const uint4*)(r1);
      uint4 d1 = *(const uint4*)(r1 + 16);
#pragma unroll
      for (int i = 0; i < 4; ++i) {
        alo[i]     = __uint_as_float(d0[i] << 16);
        ahi[i]     = __uint_as_float(d0[i] & 0xffff0000u);
        alo[4 + i] = __uint_as_float(d1[i] << 16);
        ahi[4 + i] = __uint_as_float(d1[i] & 0xffff0000u);
      }
    }
#pragma unroll
    for (int s = 0; s < 8; ++s) {
      const unsigned* r2 = lds + T2_OFF_W + tk[s] * RSTRIDE_W + qd * 4;
      uint4 d0 = *(const uint4*)(r2);
      uint4 d1 = *(const uint4*)(r2 + 16);
#pragma unroll
      for (int i = 0; i < 4; ++i) {
        alo[i]     += __uint_as_float(d0[i] << 16);
        ahi[i]     += __uint_as_float(d0[i] & 0xffff0000u);
        alo[4 + i] += __uint_as_float(d1[i] << 16);
        ahi[4 + i] += __uint_as_float(d1[i] & 0xffff0000u);
      }
    }

    union { bf16x8 s; unsigned u[4]; } ua, ub2;
#pragma unroll
    for (int i = 0; i < 4; ++i) {
      ua.u[i]  = pkbf2(fmaxf(alo[i], 0.f),     fmaxf(ahi[i], 0.f));
      ub2.u[i] = pkbf2(fmaxf(alo[4 + i], 0.f), fmaxf(ahi[4 + i], 0.f));
    }
    const bf16x8 afA = ua.s, afB = ub2.s;

    // all 4 n-tiles, then one coalesced float4 store per output row
    f32x4 acc[4];
#pragma unroll
    for (int nt = 0; nt < 4; ++nt) {
      f32x4 a;
      a[0] = bb[nt]; a[1] = bb[nt]; a[2] = bb[nt]; a[3] = bb[nt];
      a = __builtin_amdgcn_mfma_f32_16x16x32_bf16(afA, bfr[nt][0], a, 0, 0, 0);
      a = __builtin_amdgcn_mfma_f32_16x16x32_bf16(afB, bfr[nt][1], a, 0, 0, 0);
      acc[nt] = a;
    }
    float* op = out + (size_t)(b0 + qd * 4) * 64 + l15 * 4;
#pragma unroll
    for (int r = 0; r < 4; ++r) {
      f32x4 v;
      v[0] = acc[0][r]; v[1] = acc[1][r]; v[2] = acc[2][r]; v[3] = acc[3][r];
      __builtin_nontemporal_store(v, (f32x4*)(op + (size_t)r * 64));
    }
  }
}

extern "C" void kernel_launch(void* const* d_in, const int* in_sizes, int n_in,
                              void* d_out, int out_size, void* d_ws, size_t ws_size,
                              hipStream_t stream) {
  const int*   seqs  = (const int*)d_in[0];
  const int*   qtokp = (const int*)d_in[1];
  const float* embed = (const float*)d_in[2];
  const float* W1    = (const float*)d_in[3];
  const float* b1    = (const float*)d_in[4];
  const float* W2    = (const float*)d_in[5];
  const float* b2    = (const float*)d_in[6];
  float*       outp  = (float*)d_out;

  prep_kernel<<<dim3(128), dim3(64), 0, stream>>>(embed, W1, b1,
                                                  (unsigned short*)d_ws);
  lru_kernel<<<dim3(2048), dim3(256), 0, stream>>>(seqs, qtokp, W2, b2,
                                                   (const unsigned*)d_ws, outp);
}

// Round 2
// 120.255 us; speedup vs baseline: 1.0270x; 1.0270x over previous
//
#include <hip/hip_runtime.h>

// logits = relu(T1[q] + sum_s T2[t_s]) @ W2^T + b2, vocab=64 so layer-1 is
// 9 table-row gathers.
//
// R1: tables, accumulation, and MFMA switched bf16 -> fp16 packed.
//  - LDS rows hold fp16 features; the 9-row gather-accumulate is pure
//    v_pk_add_f16 on the loaded dwords (no shift/mask unpack, no fp32
//    scalar adds, no repack). ReLU = v_pk_max_f16. A-fragment is the
//    accumulator itself -> mfma_f32_16x16x32_f16.
//  - fp16 has 11 mantissa bits vs bf16's 8 -> absmax should improve.
//  - accumulator state 16 fp32 -> 8 dwords, easing the 128-VGPR cap at
//    __launch_bounds__(256,4).
//  - keeps R0's coalesced dwordx4 nontemporal stores (lane l15 owns W2
//    rows l15*4+nt) and the both-iterations token prefetch.

#define RSTRIDE_W 36                    // dwords per row (32 data + 4 pad)
#define T2_OFF_W  (64 * RSTRIDE_W)      // 2304
#define LDS_DW    (2 * 64 * RSTRIDE_W)  // 4608 dwords = 18432 B

typedef __attribute__((ext_vector_type(4))) float    f32x4;
typedef __attribute__((ext_vector_type(4))) int      i32x4;
typedef __attribute__((ext_vector_type(8))) _Float16 f16x8;

// T1 (query half, b1 folded) and T2 (memory half, 1/8 folded), fp16.
// grid 128: block = (half, token). thread j = output feature.
__global__ void prep_kernel(const float* __restrict__ embed,
                            const float* __restrict__ W1,
                            const float* __restrict__ b1,
                            unsigned short* __restrict__ T) {
  const int t    = blockIdx.x & 63;
  const int half = blockIdx.x >> 6;
  const int j    = threadIdx.x;
  const f32x4* w4 = (const f32x4*)(W1 + j * 128 + half * 64);
  const f32x4* e4 = (const f32x4*)(embed + t * 64);
  float acc = 0.f;
#pragma unroll
  for (int k = 0; k < 16; ++k) {
    f32x4 a = w4[k], b = e4[k];
    acc += a[0] * b[0] + a[1] * b[1] + a[2] * b[2] + a[3] * b[3];
  }
  const float outv = half ? acc * 0.125f : acc + b1[j];
  ((_Float16*)T)[half * (64 * 2 * RSTRIDE_W) + t * (2 * RSTRIDE_W) + j] =
      (_Float16)outv;
}

// 2048 blocks x 256 threads; each wave: 2 iters x 16 elements (one MFMA
// tile row). Lane (qd=lane>>4, m=lane&15) gathers features qd*8..+7 (ks0)
// and 32+qd*8..+7 (ks1) of its element's 9 table rows as packed fp16,
// accumulates with v_pk_add_f16, ReLUs with v_pk_max_f16, then 2 MFMAs per
// 16-col output tile.
__global__ __launch_bounds__(256, 4) void lru_kernel(
    const int*      __restrict__ seqs,
    const int*      __restrict__ qtok,
    const float*    __restrict__ W2,
    const float*    __restrict__ b2,
    const unsigned* __restrict__ T,
    float*          __restrict__ out) {
  __shared__ __align__(16) unsigned lds[LDS_DW];
  const int tid = threadIdx.x;

  {  // stage tables (1152 uint4 = 4*256 + 128)
    const uint4* src = (const uint4*)T;
    uint4*       dst = (uint4*)lds;
#pragma unroll
    for (int r = 0; r < 4; ++r) dst[tid + r * 256] = src[tid + r * 256];
    if (tid < 128) dst[tid + 1024] = src[tid + 1024];
  }

  const int lane = tid & 63;
  const int wv   = tid >> 6;
  const int qd   = lane >> 4;
  const int l15  = lane & 15;

  // B-fragments from W2 (fp32 global -> fp16): lane holds n-col l15 of MFMA
  // tile nt, mapped to W2 row (l15*4 + nt) so nt-outputs are contiguous.
  f16x8 bfr[4][2];
  float bb[4];
#pragma unroll
  for (int nt = 0; nt < 4; ++nt) {
    const int    row = l15 * 4 + nt;
    const float* wr  = W2 + row * 64 + qd * 8;
#pragma unroll
    for (int ks = 0; ks < 2; ++ks) {
      f32x4 w0 = *(const f32x4*)(wr + ks * 32);
      f32x4 w1 = *(const f32x4*)(wr + ks * 32 + 4);
      f16x8 f;
      f[0] = (_Float16)w0[0]; f[1] = (_Float16)w0[1];
      f[2] = (_Float16)w0[2]; f[3] = (_Float16)w0[3];
      f[4] = (_Float16)w1[0]; f[5] = (_Float16)w1[1];
      f[6] = (_Float16)w1[2]; f[7] = (_Float16)w1[3];
      bfr[nt][ks] = f;
    }
    bb[nt] = b2[row];
  }

  const int base = blockIdx.x * 128 + wv * 32;

  // prefetch tokens for BOTH iterations before any compute
  i32x4 tc[2][3];
  int   tq[2];
#pragma unroll
  for (int it = 0; it < 2; ++it) {
    const int  elem = base + it * 16 + l15;
    const int* srow = seqs + elem * 24;
    tc[it][0] = __builtin_nontemporal_load((const i32x4*)(srow + 12));
    tc[it][1] = __builtin_nontemporal_load((const i32x4*)(srow + 16));
    tc[it][2] = __builtin_nontemporal_load((const i32x4*)(srow + 20));
    tq[it]    = __builtin_nontemporal_load(qtok + elem);
  }
  __syncthreads();

#pragma unroll
  for (int it = 0; it < 2; ++it) {
    const int b0 = base + it * 16;
    const int tk[8] = {tc[it][0][3], tc[it][1][0], tc[it][1][1], tc[it][1][2],
                       tc[it][1][3], tc[it][2][0], tc[it][2][1], tc[it][2][2]};
    const int qt = tq[it];

    // packed fp16 accumulators: a0 = features qd*8..+7, a1 = 32+qd*8..+7
    f16x8 a0, a1;
    {
      const f16x8* r1 = (const f16x8*)(lds + qt * RSTRIDE_W + qd * 4);
      a0 = r1[0];          // dwords [qd*4 .. qd*4+3]
      a1 = r1[4];          // +16 dwords (ks1 half)
    }
#pragma unroll
    for (int s = 0; s < 8; ++s) {
      const f16x8* r2 =
          (const f16x8*)(lds + T2_OFF_W + tk[s] * RSTRIDE_W + qd * 4);
      a0 += r2[0];
      a1 += r2[4];
    }
    const f16x8 z = {(_Float16)0, (_Float16)0, (_Float16)0, (_Float16)0,
                     (_Float16)0, (_Float16)0, (_Float16)0, (_Float16)0};
    const f16x8 afA = __builtin_elementwise_max(a0, z);
    const f16x8 afB = __builtin_elementwise_max(a1, z);

    // all 4 n-tiles, then one coalesced float4 store per output row
    f32x4 acc[4];
#pragma unroll
    for (int nt = 0; nt < 4; ++nt) {
      f32x4 a;
      a[0] = bb[nt]; a[1] = bb[nt]; a[2] = bb[nt]; a[3] = bb[nt];
      a = __builtin_amdgcn_mfma_f32_16x16x32_f16(afA, bfr[nt][0], a, 0, 0, 0);
      a = __builtin_amdgcn_mfma_f32_16x16x32_f16(afB, bfr[nt][1], a, 0, 0, 0);
      acc[nt] = a;
    }
    float* op = out + (size_t)(b0 + qd * 4) * 64 + l15 * 4;
#pragma unroll
    for (int r = 0; r < 4; ++r) {
      f32x4 v;
      v[0] = acc[0][r]; v[1] = acc[1][r]; v[2] = acc[2][r]; v[3] = acc[3][r];
      __builtin_nontemporal_store(v, (f32x4*)(op + (size_t)r * 64));
    }
  }
}

extern "C" void kernel_launch(void* const* d_in, const int* in_sizes, int n_in,
                              void* d_out, int out_size, void* d_ws, size_t ws_size,
                              hipStream_t stream) {
  const int*   seqs  = (const int*)d_in[0];
  const int*   qtokp = (const int*)d_in[1];
  const float* embed = (const float*)d_in[2];
  const float* W1    = (const float*)d_in[3];
  const float* b1    = (const float*)d_in[4];
  const float* W2    = (const float*)d_in[5];
  const float* b2    = (const float*)d_in[6];
  float*       outp  = (float*)d_out;

  prep_kernel<<<dim3(128), dim3(64), 0, stream>>>(embed, W1, b1,
                                                  (unsigned short*)d_ws);
  lru_kernel<<<dim3(2048), dim3(256), 0, stream>>>(seqs, qtokp, W2, b2,
                                                   (const unsigned*)d_ws, outp);
}

// Round 3
// 113.087 us; speedup vs baseline: 1.0921x; 1.0634x over previous
//
#include <hip/hip_runtime.h>

// logits = relu(T1[q] + sum_s T2[t_s]) @ W2^T + b2, vocab=64 so layer-1 is
// 9 table-row gathers from LDS-resident fp16 tables.
//
// R2 restructure:
//  - 1024 blocks x 4 iters/wave (was 2048 x 2): staging + B-fragment
//    prologue amortized 2x, grid = exactly 4 blocks/CU (one residency
//    generation, no tail).
//  - token loads de-duplicated: lane loads ITS OWN element's 13 dwords
//    (was: all 4 qd-groups loading identical addresses -> 4x redundant
//    VMEM). Per iteration the 9 values are broadcast from lane
//    it*16+l15 via __shfl (ds_bpermute), which overlaps prior-iter MFMAs.
//  - keeps R1's fp16 packed gather-accumulate (v_pk_add_f16 directly on
//    LDS dwords, v_pk_max_f16 ReLU, A-fragment = accumulator) and R0's
//    coalesced nontemporal dwordx4 stores (lane l15 owns W2 rows l15*4+nt).

#define RSTRIDE_W 36                    // dwords per row (32 data + 4 pad)
#define T2_OFF_W  (64 * RSTRIDE_W)      // 2304
#define LDS_DW    (2 * 64 * RSTRIDE_W)  // 4608 dwords = 18432 B

typedef __attribute__((ext_vector_type(4))) float    f32x4;
typedef __attribute__((ext_vector_type(4))) int      i32x4;
typedef __attribute__((ext_vector_type(8))) _Float16 f16x8;

// T1 (query half, b1 folded) and T2 (memory half, 1/8 folded), fp16.
// grid 128: block = (half, token). thread j = output feature.
__global__ void prep_kernel(const float* __restrict__ embed,
                            const float* __restrict__ W1,
                            const float* __restrict__ b1,
                            unsigned short* __restrict__ T) {
  const int t    = blockIdx.x & 63;
  const int half = blockIdx.x >> 6;
  const int j    = threadIdx.x;
  const f32x4* w4 = (const f32x4*)(W1 + j * 128 + half * 64);
  const f32x4* e4 = (const f32x4*)(embed + t * 64);
  float acc = 0.f;
#pragma unroll
  for (int k = 0; k < 16; ++k) {
    f32x4 a = w4[k], b = e4[k];
    acc += a[0] * b[0] + a[1] * b[1] + a[2] * b[2] + a[3] * b[3];
  }
  const float outv = half ? acc * 0.125f : acc + b1[j];
  ((_Float16*)T)[half * (64 * 2 * RSTRIDE_W) + t * (2 * RSTRIDE_W) + j] =
      (_Float16)outv;
}

// 1024 blocks x 256 threads; each wave: 4 iters x 16 elements (one MFMA
// tile row each). Lane (qd=lane>>4, m=lane&15) gathers features qd*8..+7
// (ks0) and 32+qd*8..+7 (ks1) of its element's 9 table rows as packed
// fp16, accumulates with v_pk_add_f16, ReLUs, then 2 MFMAs per 16-col
// output tile.
__global__ __launch_bounds__(256, 4) void lru_kernel(
    const int*      __restrict__ seqs,
    const int*      __restrict__ qtok,
    const float*    __restrict__ W2,
    const float*    __restrict__ b2,
    const unsigned* __restrict__ T,
    float*          __restrict__ out) {
  __shared__ __align__(16) unsigned lds[LDS_DW];
  const int tid = threadIdx.x;

  {  // stage tables (1152 uint4 = 4*256 + 128)
    const uint4* src = (const uint4*)T;
    uint4*       dst = (uint4*)lds;
#pragma unroll
    for (int r = 0; r < 4; ++r) dst[tid + r * 256] = src[tid + r * 256];
    if (tid < 128) dst[tid + 1024] = src[tid + 1024];
  }

  const int lane = tid & 63;
  const int wv   = tid >> 6;
  const int qd   = lane >> 4;
  const int l15  = lane & 15;

  // B-fragments from W2 (fp32 global -> fp16): lane holds n-col l15 of MFMA
  // tile nt, mapped to W2 row (l15*4 + nt) so nt-outputs are contiguous.
  f16x8 bfr[4][2];
  float bb[4];
#pragma unroll
  for (int nt = 0; nt < 4; ++nt) {
    const int    row = l15 * 4 + nt;
    const float* wr  = W2 + row * 64 + qd * 8;
#pragma unroll
    for (int ks = 0; ks < 2; ++ks) {
      f32x4 w0 = *(const f32x4*)(wr + ks * 32);
      f32x4 w1 = *(const f32x4*)(wr + ks * 32 + 4);
      f16x8 f;
      f[0] = (_Float16)w0[0]; f[1] = (_Float16)w0[1];
      f[2] = (_Float16)w0[2]; f[3] = (_Float16)w0[3];
      f[4] = (_Float16)w1[0]; f[5] = (_Float16)w1[1];
      f[6] = (_Float16)w1[2]; f[7] = (_Float16)w1[3];
      bfr[nt][ks] = f;
    }
    bb[nt] = b2[row];
  }

  // each lane loads its OWN element's tokens once (covers all 4 iters)
  const int wbase  = blockIdx.x * 256 + wv * 64;
  const int myelem = wbase + lane;
  const int* srow  = seqs + myelem * 24;
  const i32x4 t0 = __builtin_nontemporal_load((const i32x4*)(srow + 12));
  const i32x4 t1 = __builtin_nontemporal_load((const i32x4*)(srow + 16));
  const i32x4 t2 = __builtin_nontemporal_load((const i32x4*)(srow + 20));
  const int   tq = __builtin_nontemporal_load(qtok + myelem);
  __syncthreads();

#pragma unroll
  for (int it = 0; it < 4; ++it) {
    const int b0  = wbase + it * 16;
    const int src = it * 16 + l15;   // lane holding this element's tokens

    const int qt = __shfl(tq, src);
    int tk[8];
    tk[0] = __shfl(t0.w, src);
    tk[1] = __shfl(t1.x, src);
    tk[2] = __shfl(t1.y, src);
    tk[3] = __shfl(t1.z, src);
    tk[4] = __shfl(t1.w, src);
    tk[5] = __shfl(t2.x, src);
    tk[6] = __shfl(t2.y, src);
    tk[7] = __shfl(t2.z, src);

    // packed fp16 accumulators: a0 = features qd*8..+7, a1 = 32+qd*8..+7
    f16x8 a0, a1;
    {
      const f16x8* r1 = (const f16x8*)(lds + qt * RSTRIDE_W + qd * 4);
      a0 = r1[0];          // dwords [qd*4 .. qd*4+3]
      a1 = r1[4];          // +16 dwords (ks1 half)
    }
#pragma unroll
    for (int s = 0; s < 8; ++s) {
      const f16x8* r2 =
          (const f16x8*)(lds + T2_OFF_W + tk[s] * RSTRIDE_W + qd * 4);
      a0 += r2[0];
      a1 += r2[4];
    }
    const f16x8 z = {(_Float16)0, (_Float16)0, (_Float16)0, (_Float16)0,
                     (_Float16)0, (_Float16)0, (_Float16)0, (_Float16)0};
    const f16x8 afA = __builtin_elementwise_max(a0, z);
    const f16x8 afB = __builtin_elementwise_max(a1, z);

    // all 4 n-tiles, then one coalesced float4 store per output row
    f32x4 acc[4];
#pragma unroll
    for (int nt = 0; nt < 4; ++nt) {
      f32x4 a;
      a[0] = bb[nt]; a[1] = bb[nt]; a[2] = bb[nt]; a[3] = bb[nt];
      a = __builtin_amdgcn_mfma_f32_16x16x32_f16(afA, bfr[nt][0], a, 0, 0, 0);
      a = __builtin_amdgcn_mfma_f32_16x16x32_f16(afB, bfr[nt][1], a, 0, 0, 0);
      acc[nt] = a;
    }
    float* op = out + (size_t)(b0 + qd * 4) * 64 + l15 * 4;
#pragma unroll
    for (int r = 0; r < 4; ++r) {
      f32x4 v;
      v[0] = acc[0][r]; v[1] = acc[1][r]; v[2] = acc[2][r]; v[3] = acc[3][r];
      __builtin_nontemporal_store(v, (f32x4*)(op + (size_t)r * 64));
    }
  }
}

extern "C" void kernel_launch(void* const* d_in, const int* in_sizes, int n_in,
                              void* d_out, int out_size, void* d_ws, size_t ws_size,
                              hipStream_t stream) {
  const int*   seqs  = (const int*)d_in[0];
  const int*   qtokp = (const int*)d_in[1];
  const float* embed = (const float*)d_in[2];
  const float* W1    = (const float*)d_in[3];
  const float* b1    = (const float*)d_in[4];
  const float* W2    = (const float*)d_in[5];
  const float* b2    = (const float*)d_in[6];
  float*       outp  = (float*)d_out;

  prep_kernel<<<dim3(128), dim3(64), 0, stream>>>(embed, W1, b1,
                                                  (unsigned short*)d_ws);
  lru_kernel<<<dim3(1024), dim3(256), 0, stream>>>(seqs, qtokp, W2, b2,
                                                   (const unsigned*)d_ws, outp);
}